// Round 3
// baseline (270.168 us; speedup 1.0000x reference)
//
#include <hip/hip_runtime.h>
#include <hip/hip_bf16.h>

// Problem constants
constexpr int B      = 16384;
constexpr int D_IN   = 1024;
constexpr int D_OUT  = 256;
constexpr int NCLS   = 1000;
constexpr int CPAD   = 1024;   // padded class count (grid-friendly)

// ---------------- workspace layout (byte offsets) ----------------
// Wb   : 512*1024 bf16  (rows 0-255 = W1, 256-511 = W2)   1 MiB
// s    : CPAD*D_IN f32   (per-class sums, padded)          4 MiB
// Z    : CPAD*D_OUT f32                                    1 MiB
// zeroed region: T[1024] f32, cnt[1024], offs[1024], cursor[1024]
// rowlist[B] int
constexpr size_t OFF_WB   = 0;
constexpr size_t OFF_S    = OFF_WB  + (size_t)512 * D_IN * 2;
constexpr size_t OFF_Z    = OFF_S   + (size_t)CPAD * D_IN * 4;
constexpr size_t OFF_T    = OFF_Z   + (size_t)CPAD * D_OUT * 4;
constexpr size_t OFF_CNT  = OFF_T   + (size_t)CPAD * 4;
constexpr size_t OFF_OFFS = OFF_CNT + (size_t)CPAD * 4;
constexpr size_t OFF_CUR  = OFF_OFFS+ (size_t)CPAD * 4;
constexpr size_t OFF_ROWL = OFF_CUR + (size_t)CPAD * 4;
// zeroed words: T + cnt + offs + cursor = 4*1024 words
constexpr int ZERO_WORDS = 4 * CPAD;

typedef short bf16x8 __attribute__((ext_vector_type(8)));
typedef float f32x4  __attribute__((ext_vector_type(4)));

// fp32 -> bf16 round-to-nearest-even
__device__ __forceinline__ unsigned short f2bf(float f) {
    unsigned int u = __float_as_uint(f);
    return (unsigned short)((u + 0x7FFFu + ((u >> 16) & 1u)) >> 16);
}

__device__ __forceinline__ void async16(const unsigned short* g, unsigned short* l) {
    __builtin_amdgcn_global_load_lds(
        (const __attribute__((address_space(1))) void*)g,
        (__attribute__((address_space(3))) void*)l,
        16, 0, 0);
}

// ---------------- small kernels ----------------

__global__ void zero_kernel(int* p, int n) {
    int i = blockIdx.x * blockDim.x + threadIdx.x;
    if (i < n) p[i] = 0;
}

__global__ void hist_kernel(const int* __restrict__ label, int* __restrict__ cnt) {
    int i = blockIdx.x * blockDim.x + threadIdx.x;
    if (i < B) atomicAdd(&cnt[label[i]], 1);
}

__global__ void prefix_kernel(const int* __restrict__ cnt, int* __restrict__ offs) {
    __shared__ int bufA[1024];
    __shared__ int bufB[1024];
    int t = threadIdx.x;
    int v = (t < NCLS) ? cnt[t] : 0;
    bufA[t] = v;
    __syncthreads();
    int* src = bufA;
    int* dst = bufB;
    for (int off = 1; off < 1024; off <<= 1) {
        int sv = src[t];
        if (t >= off) sv += src[t - off];
        dst[t] = sv;
        __syncthreads();
        int* tmp = src; src = dst; dst = tmp;
    }
    if (t < NCLS) offs[t] = src[t] - v;
}

__global__ void scatter_kernel(const int* __restrict__ label,
                               const int* __restrict__ offs,
                               int* __restrict__ cursor,
                               int* __restrict__ rowlist) {
    int i = blockIdx.x * blockDim.x + threadIdx.x;
    if (i < B) {
        int c = label[i];
        int p = atomicAdd(&cursor[c], 1);
        rowlist[offs[c] + p] = i;
    }
}

// concat-convert W1,W2 -> Wb [512][1024] bf16
__global__ void cvt_w_kernel(const float* __restrict__ W1, const float* __restrict__ W2,
                             unsigned short* __restrict__ dst) {
    int i = (blockIdx.x * blockDim.x + threadIdx.x) * 8;
    const float* src = (i < D_OUT * D_IN) ? (W1 + i) : (W2 + (i - D_OUT * D_IN));
    float4 a = *(const float4*)(src);
    float4 b = *(const float4*)(src + 4);
    union { unsigned short u[8]; ushort4 q[2]; } r;
    r.u[0] = f2bf(a.x); r.u[1] = f2bf(a.y); r.u[2] = f2bf(a.z); r.u[3] = f2bf(a.w);
    r.u[4] = f2bf(b.x); r.u[5] = f2bf(b.y); r.u[6] = f2bf(b.z); r.u[7] = f2bf(b.w);
    *(ushort4*)(dst + i)     = r.q[0];
    *(ushort4*)(dst + i + 4) = r.q[1];
}

// per-class fp32 column sums of x (block c, thread covers 4 cols) + grand total T
__global__ void segsum_kernel(const float* __restrict__ x,
                              const int* __restrict__ offs,
                              const int* __restrict__ cnt,
                              const int* __restrict__ rowlist,
                              float* __restrict__ s,
                              float* __restrict__ T) {
    int c = blockIdx.x;            // 0..1023
    int col = threadIdx.x * 4;     // 256 threads * 4 cols = 1024
    float4 acc = {0.f, 0.f, 0.f, 0.f};
    if (c < NCLS) {
        int o = offs[c], n = cnt[c];
        for (int r = 0; r < n; ++r) {
            int row = rowlist[o + r];
            float4 v = *(const float4*)(x + (size_t)row * D_IN + col);
            acc.x += v.x; acc.y += v.y; acc.z += v.z; acc.w += v.w;
        }
    }
    *(float4*)(s + (size_t)c * D_IN + col) = acc;
    if (c < NCLS) {
        atomicAdd(&T[col + 0], acc.x);
        atomicAdd(&T[col + 1], acc.y);
        atomicAdd(&T[col + 2], acc.z);
        atomicAdd(&T[col + 3], acc.w);
    }
}

// Z[c] = ((T - s_c)/d_c) @ W2^T + b2 ; MFMA, tile 64x64, BK=32, 4 waves (2x2 of 32x32)
__global__ __launch_bounds__(256)
void meanz_kernel(const float* __restrict__ s,
                  const float* __restrict__ T,
                  const int* __restrict__ cnt,
                  const unsigned short* __restrict__ Wb,
                  const float* __restrict__ b2,
                  float* __restrict__ Z) {
    __shared__ unsigned short As[64 * 32];
    __shared__ unsigned short Bs[64 * 32];

    const int tid  = threadIdx.x;
    const int wave = tid >> 6;
    const int lane = tid & 63;
    const int quad = lane >> 4;
    const int l16  = lane & 15;
    const int bm   = blockIdx.x * 64;   // class base
    const int bn   = blockIdx.y * 64;   // out-col base
    const int wm   = (wave >> 1) * 32;
    const int wn   = (wave & 1) * 32;

    const int arow = tid >> 2;          // 0..63
    const int akc  = (tid & 3) * 8;     // 0,8,16,24

    const int cls = bm + arow;
    const int d   = B - cnt[cls];       // cnt[c]=0 for pad classes
    const float scale = (d > 0) ? 1.f / (float)d : 0.f;
    const float* sp = s + (size_t)cls * D_IN + akc;
    const unsigned short* wp = Wb + (size_t)(256 + bn + arow) * D_IN + akc;

    f32x4 acc[2][2] = {};

    for (int k0 = 0; k0 < D_IN; k0 += 32) {
        float4 s0 = *(const float4*)(sp + k0);
        float4 s1 = *(const float4*)(sp + k0 + 4);
        float4 t0 = *(const float4*)(T + k0 + akc);
        float4 t1 = *(const float4*)(T + k0 + akc + 4);
        bf16x8 wv = *(const bf16x8*)(wp + k0);
        __syncthreads();
        union { unsigned short u[8]; bf16x8 v; } m;
        m.u[0] = f2bf((t0.x - s0.x) * scale);
        m.u[1] = f2bf((t0.y - s0.y) * scale);
        m.u[2] = f2bf((t0.z - s0.z) * scale);
        m.u[3] = f2bf((t0.w - s0.w) * scale);
        m.u[4] = f2bf((t1.x - s1.x) * scale);
        m.u[5] = f2bf((t1.y - s1.y) * scale);
        m.u[6] = f2bf((t1.z - s1.z) * scale);
        m.u[7] = f2bf((t1.w - s1.w) * scale);
        *(bf16x8*)(As + arow * 32 + akc) = m.v;
        *(bf16x8*)(Bs + arow * 32 + akc) = wv;
        __syncthreads();

        bf16x8 af[2], bfr[2];
#pragma unroll
        for (int t = 0; t < 2; ++t) {
            af[t]  = *(const bf16x8*)&As[(wm + t * 16 + l16) * 32 + quad * 8];
            bfr[t] = *(const bf16x8*)&Bs[(wn + t * 16 + l16) * 32 + quad * 8];
        }
#pragma unroll
        for (int i = 0; i < 2; ++i)
#pragma unroll
            for (int j = 0; j < 2; ++j)
                acc[i][j] = __builtin_amdgcn_mfma_f32_16x16x32_bf16(af[i], bfr[j], acc[i][j], 0, 0, 0);
    }

#pragma unroll
    for (int j = 0; j < 2; ++j) {
        const int n = bn + wn + j * 16 + l16;
        const float bias = b2[n];
#pragma unroll
        for (int i = 0; i < 2; ++i)
#pragma unroll
            for (int r = 0; r < 4; ++r) {
                const int c = bm + wm + i * 16 + quad * 4 + r;
                Z[(size_t)c * D_OUT + n] = acc[i][j][r] + bias;
            }
    }
}

// out = x @ W1^T + b1 + Z[label]  — 128x128 tile, BK=32, fused fp32->bf16 A staging
__global__ __launch_bounds__(256)
void gemm1_kernel(const float* __restrict__ x,
                  const unsigned short* __restrict__ Wb,
                  const float* __restrict__ b1,
                  const float* __restrict__ Z,
                  const int* __restrict__ label,
                  float* __restrict__ out) {
    __shared__ unsigned short As[128 * 32];
    __shared__ unsigned short Bs[128 * 32];

    const int tid  = threadIdx.x;
    const int wave = tid >> 6;
    const int lane = tid & 63;
    const int quad = lane >> 4;
    const int l16  = lane & 15;
    const int bm   = blockIdx.x * 128;
    const int bn   = blockIdx.y * 128;   // 0 or 128 (within D_OUT)
    const int wm   = (wave >> 1) * 64;
    const int wn   = (wave & 1) * 64;

    const int arow = tid >> 1;           // 0..127
    const int akc  = (tid & 1) * 16;     // 0 or 16
    const float* aptr = x + (size_t)(bm + arow) * D_IN + akc;

    f32x4 acc[4][4] = {};

    for (int k0 = 0; k0 < D_IN; k0 += 32) {
        // A global loads issued before the barrier (latency hidden by barrier wait)
        float4 a0 = *(const float4*)(aptr + k0);
        float4 a1 = *(const float4*)(aptr + k0 + 4);
        float4 a2 = *(const float4*)(aptr + k0 + 8);
        float4 a3 = *(const float4*)(aptr + k0 + 12);
        __syncthreads();   // previous iteration's LDS reads complete
        // B-tile via async copy: 512 chunks of 16B, 2 per thread
#pragma unroll
        for (int c = 0; c < 2; ++c) {
            const int wbase = c * 256 + wave * 64;
            const int idx   = wbase + lane;
            const int row   = idx >> 2;
            const int cc    = idx & 3;
            async16(Wb + (size_t)(bn + row) * D_IN + k0 + cc * 8, Bs + (size_t)wbase * 8);
        }
        // A-tile: convert + LDS write (16 bf16 per thread = 2x 16B)
        union { unsigned short u[16]; bf16x8 v[2]; } r;
        r.u[0]  = f2bf(a0.x); r.u[1]  = f2bf(a0.y); r.u[2]  = f2bf(a0.z); r.u[3]  = f2bf(a0.w);
        r.u[4]  = f2bf(a1.x); r.u[5]  = f2bf(a1.y); r.u[6]  = f2bf(a1.z); r.u[7]  = f2bf(a1.w);
        r.u[8]  = f2bf(a2.x); r.u[9]  = f2bf(a2.y); r.u[10] = f2bf(a2.z); r.u[11] = f2bf(a2.w);
        r.u[12] = f2bf(a3.x); r.u[13] = f2bf(a3.y); r.u[14] = f2bf(a3.z); r.u[15] = f2bf(a3.w);
        *(bf16x8*)(As + arow * 32 + akc)     = r.v[0];
        *(bf16x8*)(As + arow * 32 + akc + 8) = r.v[1];
        __syncthreads();   // drains vmcnt (async B) + lgkm (A writes)

        bf16x8 af[4], bfr[4];
#pragma unroll
        for (int t = 0; t < 4; ++t) {
            af[t]  = *(const bf16x8*)&As[(wm + t * 16 + l16) * 32 + quad * 8];
            bfr[t] = *(const bf16x8*)&Bs[(wn + t * 16 + l16) * 32 + quad * 8];
        }
#pragma unroll
        for (int i = 0; i < 4; ++i)
#pragma unroll
            for (int j = 0; j < 4; ++j)
                acc[i][j] = __builtin_amdgcn_mfma_f32_16x16x32_bf16(af[i], bfr[j], acc[i][j], 0, 0, 0);
    }

    // epilogue: out[m][n] = acc + b1[n] + Z[label[m]][n]
    int zrow[4][4];
#pragma unroll
    for (int i = 0; i < 4; ++i)
#pragma unroll
        for (int r = 0; r < 4; ++r)
            zrow[i][r] = label[bm + wm + i * 16 + quad * 4 + r] * D_OUT;

#pragma unroll
    for (int j = 0; j < 4; ++j) {
        const int n = bn + wn + j * 16 + l16;
        const float bias = b1[n];
#pragma unroll
        for (int i = 0; i < 4; ++i)
#pragma unroll
            for (int r = 0; r < 4; ++r) {
                const int m = bm + wm + i * 16 + quad * 4 + r;
                out[(size_t)m * D_OUT + n] = acc[i][j][r] + bias + Z[zrow[i][r] + n];
            }
    }
}

// ---------------- launcher ----------------
extern "C" void kernel_launch(void* const* d_in, const int* in_sizes, int n_in,
                              void* d_out, int out_size, void* d_ws, size_t ws_size,
                              hipStream_t stream) {
    const float* x    = (const float*)d_in[0];
    const int*   lab  = (const int*)d_in[1];
    const float* W1_w = (const float*)d_in[2];
    const float* W1_b = (const float*)d_in[3];
    const float* W2_w = (const float*)d_in[4];
    const float* W2_b = (const float*)d_in[5];
    float* out = (float*)d_out;

    char* ws = (char*)d_ws;
    unsigned short* Wb = (unsigned short*)(ws + OFF_WB);
    float* s   = (float*)(ws + OFF_S);
    float* Z   = (float*)(ws + OFF_Z);
    float* T   = (float*)(ws + OFF_T);
    int* cnt     = (int*)(ws + OFF_CNT);
    int* offs    = (int*)(ws + OFF_OFFS);
    int* cursor  = (int*)(ws + OFF_CUR);
    int* rowlist = (int*)(ws + OFF_ROWL);

    // 1. zero T/cnt/offs/cursor (contiguous)
    zero_kernel<<<(ZERO_WORDS + 255) / 256, 256, 0, stream>>>((int*)T, ZERO_WORDS);
    // 2. histogram
    hist_kernel<<<B / 256, 256, 0, stream>>>(lab, cnt);
    // 3. exclusive prefix
    prefix_kernel<<<1, 1024, 0, stream>>>(cnt, offs);
    // 4. counting-sort scatter
    scatter_kernel<<<B / 256, 256, 0, stream>>>(lab, offs, cursor, rowlist);
    // 5. weights -> bf16 (independent; early for overlap)
    cvt_w_kernel<<<(512 * D_IN / 8) / 256, 256, 0, stream>>>(W1_w, W2_w, Wb);
    // 6. per-class fp32 sums + grand total (also warms x into L3)
    segsum_kernel<<<CPAD, 256, 0, stream>>>(x, offs, cnt, rowlist, s, T);
    // 7. Z table via small MFMA GEMM
    dim3 zgrid(CPAD / 64, D_OUT / 64);
    meanz_kernel<<<zgrid, 256, 0, stream>>>(s, T, cnt, Wb, W2_b, Z);
    // 8. main GEMM with fused cvt + bias + Z gather
    dim3 ggrid(B / 128, D_OUT / 128);
    gemm1_kernel<<<ggrid, 256, 0, stream>>>(x, Wb, W1_b, Z, lab, out);
}

// Round 4
// 189.529 us; speedup vs baseline: 1.4255x; 1.4255x over previous
//
#include <hip/hip_runtime.h>
#include <hip/hip_bf16.h>

// Problem constants
constexpr int B      = 16384;
constexpr int D_IN   = 1024;
constexpr int D_OUT  = 256;
constexpr int NCLS   = 1000;
constexpr int CPAD   = 1024;   // padded class count

// ---------------- workspace layout (byte offsets) ----------------
constexpr size_t OFF_WB   = 0;                                   // 512*1024 bf16
constexpr size_t OFF_S    = OFF_WB  + (size_t)512 * D_IN * 2;    // CPAD*D_IN f32
constexpr size_t OFF_Z    = OFF_S   + (size_t)CPAD * D_IN * 4;   // CPAD*D_OUT f32
constexpr size_t OFF_T    = OFF_Z   + (size_t)CPAD * D_OUT * 4;  // D_IN f32 (zeroed)
constexpr size_t OFF_CNT  = OFF_T   + (size_t)D_IN * 4;          // CPAD int (zeroed)
constexpr size_t OFF_OFFS = OFF_CNT + (size_t)CPAD * 4;          // CPAD int (zeroed)
constexpr size_t OFF_CUR  = OFF_OFFS+ (size_t)CPAD * 4;          // CPAD int (zeroed)
constexpr size_t OFF_ROWL = OFF_CUR + (size_t)CPAD * 4;          // B int
// zeroed words: T(1024) + cnt + offs + cursor
constexpr int ZERO_WORDS = D_IN + 3 * CPAD;

typedef short bf16x8 __attribute__((ext_vector_type(8)));
typedef float f32x4  __attribute__((ext_vector_type(4)));

// fp32 -> bf16 round-to-nearest-even
__device__ __forceinline__ unsigned short f2bf(float f) {
    unsigned int u = __float_as_uint(f);
    return (unsigned short)((u + 0x7FFFu + ((u >> 16) & 1u)) >> 16);
}

__device__ __forceinline__ void async16(const unsigned short* g, unsigned short* l) {
    __builtin_amdgcn_global_load_lds(
        (const __attribute__((address_space(1))) void*)g,
        (__attribute__((address_space(3))) void*)l,
        16, 0, 0);
}

// ---------------- small kernels ----------------

__global__ void zero_kernel(int* p, int n) {
    int i = blockIdx.x * blockDim.x + threadIdx.x;
    if (i < n) p[i] = 0;
}

__global__ void hist_kernel(const int* __restrict__ label, int* __restrict__ cnt) {
    int i = blockIdx.x * blockDim.x + threadIdx.x;
    if (i < B) atomicAdd(&cnt[label[i]], 1);
}

__global__ void prefix_kernel(const int* __restrict__ cnt, int* __restrict__ offs) {
    __shared__ int bufA[1024];
    __shared__ int bufB[1024];
    int t = threadIdx.x;
    int v = (t < NCLS) ? cnt[t] : 0;
    bufA[t] = v;
    __syncthreads();
    int* src = bufA;
    int* dst = bufB;
    for (int off = 1; off < 1024; off <<= 1) {
        int sv = src[t];
        if (t >= off) sv += src[t - off];
        dst[t] = sv;
        __syncthreads();
        int* tmp = src; src = dst; dst = tmp;
    }
    if (t < NCLS) offs[t] = src[t] - v;
}

__global__ void scatter_kernel(const int* __restrict__ label,
                               const int* __restrict__ offs,
                               int* __restrict__ cursor,
                               int* __restrict__ rowlist) {
    int i = blockIdx.x * blockDim.x + threadIdx.x;
    if (i < B) {
        int c = label[i];
        int p = atomicAdd(&cursor[c], 1);
        rowlist[offs[c] + p] = i;
    }
}

// concat-convert W1,W2 -> Wb [512][1024] bf16
__global__ void cvt_w_kernel(const float* __restrict__ W1, const float* __restrict__ W2,
                             unsigned short* __restrict__ dst) {
    int i = (blockIdx.x * blockDim.x + threadIdx.x) * 8;
    const float* src = (i < D_OUT * D_IN) ? (W1 + i) : (W2 + (i - D_OUT * D_IN));
    float4 a = *(const float4*)(src);
    float4 b = *(const float4*)(src + 4);
    union { unsigned short u[8]; ushort4 q[2]; } r;
    r.u[0] = f2bf(a.x); r.u[1] = f2bf(a.y); r.u[2] = f2bf(a.z); r.u[3] = f2bf(a.w);
    r.u[4] = f2bf(b.x); r.u[5] = f2bf(b.y); r.u[6] = f2bf(b.z); r.u[7] = f2bf(b.w);
    *(ushort4*)(dst + i)     = r.q[0];
    *(ushort4*)(dst + i + 4) = r.q[1];
}

// per-class fp32 column sums of x; NO global atomics (pad classes write zeros)
__global__ void segsum_kernel(const float* __restrict__ x,
                              const int* __restrict__ offs,
                              const int* __restrict__ cnt,
                              const int* __restrict__ rowlist,
                              float* __restrict__ s) {
    int c = blockIdx.x;            // 0..1023
    int col = threadIdx.x * 4;     // 256 threads * 4 cols = 1024
    float4 acc = {0.f, 0.f, 0.f, 0.f};
    if (c < NCLS) {
        int o = offs[c], n = cnt[c];
        int r = 0;
        for (; r + 4 <= n; r += 4) {
            int i0 = rowlist[o + r + 0];
            int i1 = rowlist[o + r + 1];
            int i2 = rowlist[o + r + 2];
            int i3 = rowlist[o + r + 3];
            float4 v0 = *(const float4*)(x + (size_t)i0 * D_IN + col);
            float4 v1 = *(const float4*)(x + (size_t)i1 * D_IN + col);
            float4 v2 = *(const float4*)(x + (size_t)i2 * D_IN + col);
            float4 v3 = *(const float4*)(x + (size_t)i3 * D_IN + col);
            acc.x += (v0.x + v1.x) + (v2.x + v3.x);
            acc.y += (v0.y + v1.y) + (v2.y + v3.y);
            acc.z += (v0.z + v1.z) + (v2.z + v3.z);
            acc.w += (v0.w + v1.w) + (v2.w + v3.w);
        }
        for (; r < n; ++r) {
            int i0 = rowlist[o + r];
            float4 v = *(const float4*)(x + (size_t)i0 * D_IN + col);
            acc.x += v.x; acc.y += v.y; acc.z += v.z; acc.w += v.w;
        }
    }
    *(float4*)(s + (size_t)c * D_IN + col) = acc;
}

// T = column-sum of s; 8 blocks x 128 classes -> only 8 atomics per address
__global__ void tsum_kernel(const float* __restrict__ s, float* __restrict__ T) {
    int col = threadIdx.x * 4;
    int c0 = blockIdx.x * (CPAD / 8);
    float4 acc = {0.f, 0.f, 0.f, 0.f};
    for (int c = 0; c < CPAD / 8; ++c) {
        float4 v = *(const float4*)(s + (size_t)(c0 + c) * D_IN + col);
        acc.x += v.x; acc.y += v.y; acc.z += v.z; acc.w += v.w;
    }
    atomicAdd(&T[col + 0], acc.x);
    atomicAdd(&T[col + 1], acc.y);
    atomicAdd(&T[col + 2], acc.z);
    atomicAdd(&T[col + 3], acc.w);
}

// Z[c] = ((T - s_c)/d_c) @ W2^T + b2 ; MFMA 64x64 tile, BK=32
__global__ __launch_bounds__(256)
void meanz_kernel(const float* __restrict__ s,
                  const float* __restrict__ T,
                  const int* __restrict__ cnt,
                  const unsigned short* __restrict__ Wb,
                  const float* __restrict__ b2,
                  float* __restrict__ Z) {
    __shared__ unsigned short As[64 * 32];
    __shared__ unsigned short Bs[64 * 32];

    const int tid  = threadIdx.x;
    const int wave = tid >> 6;
    const int lane = tid & 63;
    const int quad = lane >> 4;
    const int l16  = lane & 15;
    const int bm   = blockIdx.x * 64;   // class base
    const int bn   = blockIdx.y * 64;   // out-col base
    const int wm   = (wave >> 1) * 32;
    const int wn   = (wave & 1) * 32;

    const int arow = tid >> 2;          // 0..63
    const int akc  = (tid & 3) * 8;     // 0,8,16,24

    const int cls = bm + arow;
    const int d   = B - cnt[cls];
    const float scale = (d > 0) ? 1.f / (float)d : 0.f;
    const float* sp = s + (size_t)cls * D_IN + akc;
    const unsigned short* wp = Wb + (size_t)(256 + bn + arow) * D_IN + akc;

    f32x4 acc[2][2] = {};

    for (int k0 = 0; k0 < D_IN; k0 += 32) {
        float4 s0 = *(const float4*)(sp + k0);
        float4 s1 = *(const float4*)(sp + k0 + 4);
        float4 t0 = *(const float4*)(T + k0 + akc);
        float4 t1 = *(const float4*)(T + k0 + akc + 4);
        bf16x8 wv = *(const bf16x8*)(wp + k0);
        __syncthreads();
        union { unsigned short u[8]; bf16x8 v; } m;
        m.u[0] = f2bf((t0.x - s0.x) * scale);
        m.u[1] = f2bf((t0.y - s0.y) * scale);
        m.u[2] = f2bf((t0.z - s0.z) * scale);
        m.u[3] = f2bf((t0.w - s0.w) * scale);
        m.u[4] = f2bf((t1.x - s1.x) * scale);
        m.u[5] = f2bf((t1.y - s1.y) * scale);
        m.u[6] = f2bf((t1.z - s1.z) * scale);
        m.u[7] = f2bf((t1.w - s1.w) * scale);
        *(bf16x8*)(As + arow * 32 + akc) = m.v;
        *(bf16x8*)(Bs + arow * 32 + akc) = wv;
        __syncthreads();

        bf16x8 af[2], bfr[2];
#pragma unroll
        for (int t = 0; t < 2; ++t) {
            af[t]  = *(const bf16x8*)&As[(wm + t * 16 + l16) * 32 + quad * 8];
            bfr[t] = *(const bf16x8*)&Bs[(wn + t * 16 + l16) * 32 + quad * 8];
        }
#pragma unroll
        for (int i = 0; i < 2; ++i)
#pragma unroll
            for (int j = 0; j < 2; ++j)
                acc[i][j] = __builtin_amdgcn_mfma_f32_16x16x32_bf16(af[i], bfr[j], acc[i][j], 0, 0, 0);
    }

#pragma unroll
    for (int j = 0; j < 2; ++j) {
        const int n = bn + wn + j * 16 + l16;
        const float bias = b2[n];
#pragma unroll
        for (int i = 0; i < 2; ++i)
#pragma unroll
            for (int r = 0; r < 4; ++r) {
                const int c = bm + wm + i * 16 + quad * 4 + r;
                Z[(size_t)c * D_OUT + n] = acc[i][j][r] + bias;
            }
    }
}

// out = x @ W1^T + b1 + Z[label]  — 128x128 tile, BK=32, fused fp32->bf16 A staging
__global__ __launch_bounds__(256)
void gemm1_kernel(const float* __restrict__ x,
                  const unsigned short* __restrict__ Wb,
                  const float* __restrict__ b1,
                  const float* __restrict__ Z,
                  const int* __restrict__ label,
                  float* __restrict__ out) {
    __shared__ unsigned short As[128 * 32];
    __shared__ unsigned short Bs[128 * 32];

    const int tid  = threadIdx.x;
    const int wave = tid >> 6;
    const int lane = tid & 63;
    const int quad = lane >> 4;
    const int l16  = lane & 15;
    const int bm   = blockIdx.x * 128;
    const int bn   = blockIdx.y * 128;
    const int wm   = (wave >> 1) * 64;
    const int wn   = (wave & 1) * 64;

    const int arow = tid >> 1;           // 0..127
    const int akc  = (tid & 1) * 16;     // 0 or 16
    const float* aptr = x + (size_t)(bm + arow) * D_IN + akc;

    f32x4 acc[4][4] = {};

    for (int k0 = 0; k0 < D_IN; k0 += 32) {
        float4 a0 = *(const float4*)(aptr + k0);
        float4 a1 = *(const float4*)(aptr + k0 + 4);
        float4 a2 = *(const float4*)(aptr + k0 + 8);
        float4 a3 = *(const float4*)(aptr + k0 + 12);
        __syncthreads();
#pragma unroll
        for (int c = 0; c < 2; ++c) {
            const int wbase = c * 256 + wave * 64;
            const int idx   = wbase + lane;
            const int row   = idx >> 2;
            const int cc    = idx & 3;
            async16(Wb + (size_t)(bn + row) * D_IN + k0 + cc * 8, Bs + (size_t)wbase * 8);
        }
        union { unsigned short u[16]; bf16x8 v[2]; } r;
        r.u[0]  = f2bf(a0.x); r.u[1]  = f2bf(a0.y); r.u[2]  = f2bf(a0.z); r.u[3]  = f2bf(a0.w);
        r.u[4]  = f2bf(a1.x); r.u[5]  = f2bf(a1.y); r.u[6]  = f2bf(a1.z); r.u[7]  = f2bf(a1.w);
        r.u[8]  = f2bf(a2.x); r.u[9]  = f2bf(a2.y); r.u[10] = f2bf(a2.z); r.u[11] = f2bf(a2.w);
        r.u[12] = f2bf(a3.x); r.u[13] = f2bf(a3.y); r.u[14] = f2bf(a3.z); r.u[15] = f2bf(a3.w);
        *(bf16x8*)(As + arow * 32 + akc)     = r.v[0];
        *(bf16x8*)(As + arow * 32 + akc + 8) = r.v[1];
        __syncthreads();

        bf16x8 af[4], bfr[4];
#pragma unroll
        for (int t = 0; t < 4; ++t) {
            af[t]  = *(const bf16x8*)&As[(wm + t * 16 + l16) * 32 + quad * 8];
            bfr[t] = *(const bf16x8*)&Bs[(wn + t * 16 + l16) * 32 + quad * 8];
        }
#pragma unroll
        for (int i = 0; i < 4; ++i)
#pragma unroll
            for (int j = 0; j < 4; ++j)
                acc[i][j] = __builtin_amdgcn_mfma_f32_16x16x32_bf16(af[i], bfr[j], acc[i][j], 0, 0, 0);
    }

    int zrow[4][4];
#pragma unroll
    for (int i = 0; i < 4; ++i)
#pragma unroll
        for (int r = 0; r < 4; ++r)
            zrow[i][r] = label[bm + wm + i * 16 + quad * 4 + r] * D_OUT;

#pragma unroll
    for (int j = 0; j < 4; ++j) {
        const int n = bn + wn + j * 16 + l16;
        const float bias = b1[n];
#pragma unroll
        for (int i = 0; i < 4; ++i)
#pragma unroll
            for (int r = 0; r < 4; ++r) {
                const int m = bm + wm + i * 16 + quad * 4 + r;
                out[(size_t)m * D_OUT + n] = acc[i][j][r] + bias + Z[zrow[i][r] + n];
            }
    }
}

// ---------------- launcher ----------------
extern "C" void kernel_launch(void* const* d_in, const int* in_sizes, int n_in,
                              void* d_out, int out_size, void* d_ws, size_t ws_size,
                              hipStream_t stream) {
    const float* x    = (const float*)d_in[0];
    const int*   lab  = (const int*)d_in[1];
    const float* W1_w = (const float*)d_in[2];
    const float* W1_b = (const float*)d_in[3];
    const float* W2_w = (const float*)d_in[4];
    const float* W2_b = (const float*)d_in[5];
    float* out = (float*)d_out;

    char* ws = (char*)d_ws;
    unsigned short* Wb = (unsigned short*)(ws + OFF_WB);
    float* s   = (float*)(ws + OFF_S);
    float* Z   = (float*)(ws + OFF_Z);
    float* T   = (float*)(ws + OFF_T);
    int* cnt     = (int*)(ws + OFF_CNT);
    int* offs    = (int*)(ws + OFF_OFFS);
    int* cursor  = (int*)(ws + OFF_CUR);
    int* rowlist = (int*)(ws + OFF_ROWL);

    // 1. zero T/cnt/offs/cursor (contiguous)
    zero_kernel<<<(ZERO_WORDS + 255) / 256, 256, 0, stream>>>((int*)T, ZERO_WORDS);
    // 2. histogram
    hist_kernel<<<B / 256, 256, 0, stream>>>(lab, cnt);
    // 3. exclusive prefix
    prefix_kernel<<<1, 1024, 0, stream>>>(cnt, offs);
    // 4. counting-sort scatter
    scatter_kernel<<<B / 256, 256, 0, stream>>>(lab, offs, cursor, rowlist);
    // 5. weights -> bf16
    cvt_w_kernel<<<(512 * D_IN / 8) / 256, 256, 0, stream>>>(W1_w, W2_w, Wb);
    // 6. per-class fp32 sums (no atomics)
    segsum_kernel<<<CPAD, 256, 0, stream>>>(x, offs, cnt, rowlist, s);
    // 7. grand total from s (8-way atomic contention only)
    tsum_kernel<<<8, 256, 0, stream>>>(s, T);
    // 8. Z table via small MFMA GEMM
    dim3 zgrid(CPAD / 64, D_OUT / 64);
    meanz_kernel<<<zgrid, 256, 0, stream>>>(s, T, cnt, Wb, W2_b, Z);
    // 9. main GEMM with fused cvt + bias + Z gather
    dim3 ggrid(B / 128, D_OUT / 128);
    gemm1_kernel<<<ggrid, 256, 0, stream>>>(x, Wb, W1_b, Z, lab, out);
}